// Round 4
// baseline (1197.434 us; speedup 1.0000x reference)
//
#include <hip/hip_runtime.h>
#include <hip/hip_bf16.h>

// Problem: B=2, N=2048, E=1024, H=16, HD=64.
// CONFIRMED (R2 diagnostics): inputs fp32, output fp32.
// Internal Q/K/V/sa buffers bf16 (32 MiB ws, proven sufficient).
#define Bz 2
#define Nn 2048
#define Ee 1024
#define Hh 16
#define HD 64

typedef unsigned short u16;
typedef unsigned int u32;

__device__ __forceinline__ float bf2f(u16 u) {
    u32 v = ((u32)u) << 16;
    return __builtin_bit_cast(float, v);
}
__device__ __forceinline__ u16 f2bf(float f) {
    u32 i = __builtin_bit_cast(u32, f);
    u32 r = (i + 0x7FFFu + ((i >> 16) & 1u)) >> 16;  // RNE
    return (u16)r;
}

__global__ void ws_diag(float* out, float code) { out[0] = code; }

// ---------------------------------------------------------------------------
// Kernel 1: per-head QKV projection (fp32 in) -> bf16 k/q/v [B,H,N,64].
// x [4096,1024] f32; Wqkv [16,1024,192] f32; bqkv [16,192] f32.
// Block: 64x64 output tile (row tile mt; ft 0=k,1=q,2=v; head h).
// ---------------------------------------------------------------------------
__global__ __launch_bounds__(256) void qkv_gemm(
    const float* __restrict__ x, const float* __restrict__ W,
    const float* __restrict__ bias,
    u16* __restrict__ kbuf, u16* __restrict__ qbuf, u16* __restrict__ vbuf)
{
    const int mt = blockIdx.x;   // 0..63
    const int ft = blockIdx.y;   // 0..2 (0=k,1=q,2=v)
    const int h  = blockIdx.z;   // 0..15
    const int tid = threadIdx.x;
    const int tx = tid & 15, ty = tid >> 4;

    __shared__ float As[16][68];  // [k][m]
    __shared__ float Bs[16][68];  // [k][n]

    float acc[4][4] = {};
    const int arow = tid >> 2;          // 0..63
    const int akq  = (tid & 3) << 2;    // 0,4,8,12
    const float* xrow = x + (size_t)(mt * 64 + arow) * Ee;
    const float* wb = W + (size_t)h * Ee * 192 + ft * 64;

    for (int k0 = 0; k0 < Ee; k0 += 16) {
        float4 afl = *(const float4*)(xrow + k0 + akq);
        float4 bfl = *(const float4*)(wb + (size_t)(k0 + ty) * 192 + tx * 4);
        __syncthreads();
        As[akq + 0][arow] = afl.x;
        As[akq + 1][arow] = afl.y;
        As[akq + 2][arow] = afl.z;
        As[akq + 3][arow] = afl.w;
        *(float4*)&Bs[ty][tx * 4] = bfl;
        __syncthreads();
#pragma unroll
        for (int kk = 0; kk < 16; ++kk) {
            float4 a4 = *(const float4*)&As[kk][ty * 4];
            float4 b4 = *(const float4*)&Bs[kk][tx * 4];
            float ar[4] = {a4.x, a4.y, a4.z, a4.w};
            float br[4] = {b4.x, b4.y, b4.z, b4.w};
#pragma unroll
            for (int r = 0; r < 4; ++r)
#pragma unroll
                for (int c = 0; c < 4; ++c)
                    acc[r][c] = fmaf(ar[r], br[c], acc[r][c]);
        }
    }

    float bvv[4];
#pragma unroll
    for (int c = 0; c < 4; ++c)
        bvv[c] = bias[h * 192 + ft * 64 + tx * 4 + c];
    u16* dst = (ft == 0) ? kbuf : (ft == 1) ? qbuf : vbuf;
#pragma unroll
    for (int r = 0; r < 4; ++r) {
        int gm = mt * 64 + ty * 4 + r;
        int b = gm >> 11, n = gm & (Nn - 1);
        ushort4 o;
        o.x = f2bf(acc[r][0] + bvv[0]);
        o.y = f2bf(acc[r][1] + bvv[1]);
        o.z = f2bf(acc[r][2] + bvv[2]);
        o.w = f2bf(acc[r][3] + bvv[3]);
        *(ushort4*)&dst[(((size_t)(b * Hh + h)) * Nn + n) * HD + tx * 4] = o;
    }
}

// ---------------------------------------------------------------------------
// Kernel 2: causal flash attention over bf16 buffers, fp32 math. LDS = 64 KB.
// One block per (q-tile of 64, b*h).
// ---------------------------------------------------------------------------
__global__ __launch_bounds__(256) void attn(
    const u16* __restrict__ qbuf, const u16* __restrict__ kbuf,
    const u16* __restrict__ vbuf, u16* __restrict__ sabuf)
{
    const int qt = blockIdx.x;   // 0..31
    const int bh = blockIdx.y;   // 0..31
    const int b = bh >> 4, h = bh & 15;
    const int tid = threadIdx.x;
    const int tx = tid & 15, ty = tid >> 4;

    __shared__ float Qs[64][64];  // [d][row]
    __shared__ float Ks[64][64];  // [d][row]
    __shared__ float Ps[64][64];  // [j][row]
    __shared__ float Vs[64][64];  // [j][d]

    const u16* qb = qbuf + ((size_t)bh * Nn + qt * 64) * HD;
    const u16* kb = kbuf + (size_t)bh * Nn * HD;
    const u16* vb = vbuf + (size_t)bh * Nn * HD;

    for (int i = tid; i < 1024; i += 256) {
        int idx = i * 4;
        int row = idx >> 6, d = idx & 63;
        ushort4 v = *(const ushort4*)(qb + row * 64 + d);
        Qs[d + 0][row] = bf2f(v.x); Qs[d + 1][row] = bf2f(v.y);
        Qs[d + 2][row] = bf2f(v.z); Qs[d + 3][row] = bf2f(v.w);
    }

    float o[4][4] = {};
    float m_i[4], l_i[4];
#pragma unroll
    for (int r = 0; r < 4; ++r) { m_i[r] = -1e30f; l_i[r] = 0.f; }

    for (int kt = 0; kt <= qt; ++kt) {
        __syncthreads();
        for (int i = tid; i < 1024; i += 256) {
            int idx = i * 4;
            int row = idx >> 6, d = idx & 63;
            ushort4 kv = *(const ushort4*)(kb + (size_t)(kt * 64 + row) * 64 + d);
            Ks[d + 0][row] = bf2f(kv.x); Ks[d + 1][row] = bf2f(kv.y);
            Ks[d + 2][row] = bf2f(kv.z); Ks[d + 3][row] = bf2f(kv.w);
            ushort4 vv = *(const ushort4*)(vb + (size_t)(kt * 64 + row) * 64 + d);
            Vs[row][d + 0] = bf2f(vv.x); Vs[row][d + 1] = bf2f(vv.y);
            Vs[row][d + 2] = bf2f(vv.z); Vs[row][d + 3] = bf2f(vv.w);
        }
        __syncthreads();

        float s[4][4] = {};
#pragma unroll 8
        for (int d = 0; d < 64; ++d) {
            float4 q4 = *(const float4*)&Qs[d][ty * 4];
            float4 k4 = *(const float4*)&Ks[d][tx * 4];
            float qr[4] = {q4.x, q4.y, q4.z, q4.w};
            float kr[4] = {k4.x, k4.y, k4.z, k4.w};
#pragma unroll
            for (int r = 0; r < 4; ++r)
#pragma unroll
                for (int c = 0; c < 4; ++c)
                    s[r][c] = fmaf(qr[r], kr[c], s[r][c]);
        }

        const float sc = 0.125f;  // 1/sqrt(64)
        if (kt == qt) {
#pragma unroll
            for (int r = 0; r < 4; ++r)
#pragma unroll
                for (int c = 0; c < 4; ++c) {
                    int qg = ty * 4 + r, kg = tx * 4 + c;
                    s[r][c] = (kg <= qg) ? s[r][c] * sc : -1e30f;
                }
        } else {
#pragma unroll
            for (int r = 0; r < 4; ++r)
#pragma unroll
                for (int c = 0; c < 4; ++c) s[r][c] *= sc;
        }

#pragma unroll
        for (int r = 0; r < 4; ++r) {
            float mt_ = fmaxf(fmaxf(s[r][0], s[r][1]), fmaxf(s[r][2], s[r][3]));
#pragma unroll
            for (int off = 8; off >= 1; off >>= 1)
                mt_ = fmaxf(mt_, __shfl_xor(mt_, off, 16));
            float mn = fmaxf(m_i[r], mt_);
            float alpha = __expf(m_i[r] - mn);
            m_i[r] = mn;
            float rs = 0.f;
#pragma unroll
            for (int c = 0; c < 4; ++c) {
                s[r][c] = __expf(s[r][c] - mn);
                rs += s[r][c];
            }
#pragma unroll
            for (int off = 8; off >= 1; off >>= 1)
                rs += __shfl_xor(rs, off, 16);
            l_i[r] = l_i[r] * alpha + rs;
#pragma unroll
            for (int c = 0; c < 4; ++c) o[r][c] *= alpha;
        }

#pragma unroll
        for (int c = 0; c < 4; ++c)
#pragma unroll
            for (int r = 0; r < 4; ++r)
                Ps[tx * 4 + c][ty * 4 + r] = s[r][c];
        __syncthreads();
#pragma unroll 8
        for (int j = 0; j < 64; ++j) {
            float4 p4 = *(const float4*)&Ps[j][ty * 4];
            float4 v4 = *(const float4*)&Vs[j][tx * 4];
            float pr[4] = {p4.x, p4.y, p4.z, p4.w};
            float vr[4] = {v4.x, v4.y, v4.z, v4.w};
#pragma unroll
            for (int r = 0; r < 4; ++r)
#pragma unroll
                for (int c = 0; c < 4; ++c)
                    o[r][c] = fmaf(pr[r], vr[c], o[r][c]);
        }
    }

#pragma unroll
    for (int r = 0; r < 4; ++r) {
        float inv = 1.f / l_i[r];
        int n = qt * 64 + ty * 4 + r;
        ushort4 ov;
        ov.x = f2bf(o[r][0] * inv);
        ov.y = f2bf(o[r][1] * inv);
        ov.z = f2bf(o[r][2] * inv);
        ov.w = f2bf(o[r][3] * inv);
        *(ushort4*)&sabuf[((size_t)(b * Nn + n)) * Ee + h * 64 + tx * 4] = ov;
    }
}

// ---------------------------------------------------------------------------
// Kernel 3: output projection. sa [4096,1024] bf16 × Wout [1024,1024] f32
// + bout f32 -> out f32 [4096,1024].
// ---------------------------------------------------------------------------
__global__ __launch_bounds__(256) void out_gemm(
    const u16* __restrict__ A, const float* __restrict__ W,
    const float* __restrict__ bias, float* __restrict__ out)
{
    const int mt = blockIdx.x;  // 0..63
    const int nt = blockIdx.y;  // 0..15
    const int tid = threadIdx.x;
    const int tx = tid & 15, ty = tid >> 4;

    __shared__ float As[16][68];
    __shared__ float Bs[16][68];

    float acc[4][4] = {};
    const int arow = tid >> 2;
    const int akq  = (tid & 3) << 2;
    const u16* arp = A + (size_t)(mt * 64 + arow) * Ee;

    for (int k0 = 0; k0 < Ee; k0 += 16) {
        ushort4 av = *(const ushort4*)(arp + k0 + akq);
        float4 bfl = *(const float4*)(W + (size_t)(k0 + ty) * Ee + nt * 64 + tx * 4);
        __syncthreads();
        As[akq + 0][arow] = bf2f(av.x);
        As[akq + 1][arow] = bf2f(av.y);
        As[akq + 2][arow] = bf2f(av.z);
        As[akq + 3][arow] = bf2f(av.w);
        *(float4*)&Bs[ty][tx * 4] = bfl;
        __syncthreads();
#pragma unroll
        for (int kk = 0; kk < 16; ++kk) {
            float4 a4 = *(const float4*)&As[kk][ty * 4];
            float4 b4 = *(const float4*)&Bs[kk][tx * 4];
            float ar[4] = {a4.x, a4.y, a4.z, a4.w};
            float br[4] = {b4.x, b4.y, b4.z, b4.w};
#pragma unroll
            for (int r = 0; r < 4; ++r)
#pragma unroll
                for (int c = 0; c < 4; ++c)
                    acc[r][c] = fmaf(ar[r], br[c], acc[r][c]);
        }
    }

    float bvv[4];
#pragma unroll
    for (int c = 0; c < 4; ++c)
        bvv[c] = bias[nt * 64 + tx * 4 + c];
#pragma unroll
    for (int r = 0; r < 4; ++r) {
        int gm = mt * 64 + ty * 4 + r;
        float4 ov = make_float4(acc[r][0] + bvv[0], acc[r][1] + bvv[1],
                                acc[r][2] + bvv[2], acc[r][3] + bvv[3]);
        *(float4*)&out[(size_t)gm * Ee + nt * 64 + tx * 4] = ov;
    }
}

// ---------------------------------------------------------------------------
extern "C" void kernel_launch(void* const* d_in, const int* in_sizes, int n_in,
                              void* d_out, int out_size, void* d_ws, size_t ws_size,
                              hipStream_t stream) {
    const float* x    = (const float*)d_in[0];  // [2,2048,1024] f32
    const float* Wqkv = (const float*)d_in[1];  // [16,1024,192] f32
    const float* bqkv = (const float*)d_in[2];  // [16,192] f32
    const float* Wout = (const float*)d_in[3];  // [1024,1024] f32
    const float* bout = (const float*)d_in[4];  // [1024] f32
    float* out = (float*)d_out;                 // [2,2048,1024] f32

    const size_t SZ = (size_t)Bz * Hh * Nn * HD;   // 4,194,304 elems
    const size_t NSA = (size_t)Bz * Nn * Ee;       // 4,194,304 elems
    const size_t NEED = (3 * SZ + NSA) * sizeof(u16);  // 32 MiB

    if (ws_size < NEED) {
        ws_diag<<<1, 1, 0, stream>>>(out, 20000.0f + (float)(ws_size >> 20));
        return;
    }

    u16* ws = (u16*)d_ws;
    u16* kbuf  = ws;
    u16* qbuf  = ws + SZ;
    u16* vbuf  = ws + 2 * SZ;
    u16* sabuf = ws + 3 * SZ;

    qkv_gemm<<<dim3(64, 3, 16), 256, 0, stream>>>(x, Wqkv, bqkv, kbuf, qbuf, vbuf);
    attn<<<dim3(32, 32), 256, 0, stream>>>(qbuf, kbuf, vbuf, sabuf);
    out_gemm<<<dim3(64, 16), 256, 0, stream>>>(sabuf, Wout, bout, out);
}

// Round 5
// 393.924 us; speedup vs baseline: 3.0398x; 3.0398x over previous
//
#include <hip/hip_runtime.h>
#include <hip/hip_bf16.h>

// B=2, N=2048, E=1024, H=16, HD=64. Inputs fp32, output fp32 (R2-confirmed).
// Internal q/k/v/sa buffers bf16 in d_ws (32 MiB). All matmuls on bf16 MFMA.
#define Bz 2
#define Nn 2048
#define Ee 1024
#define Hh 16
#define HD 64

typedef unsigned short u16;
typedef unsigned int u32;

typedef __bf16 bf16x8 __attribute__((ext_vector_type(8)));
typedef float f32x4 __attribute__((ext_vector_type(4)));
typedef float f32x16 __attribute__((ext_vector_type(16)));

__device__ __forceinline__ float bf2f(u16 u) {
    u32 v = ((u32)u) << 16;
    return __builtin_bit_cast(float, v);
}
__device__ __forceinline__ u16 f2bf(float f) {
    u32 i = __builtin_bit_cast(u32, f);
    u32 r = (i + 0x7FFFu + ((i >> 16) & 1u)) >> 16;  // RNE
    return (u16)r;
}
__device__ __forceinline__ u32 pack2(float a, float b) {
    return (u32)f2bf(a) | ((u32)f2bf(b) << 16);
}
__device__ __forceinline__ bf16x8 ld_frag(const u16* p) {
    return __builtin_bit_cast(bf16x8, *(const uint4*)p);
}
__device__ __forceinline__ f32x4 zero4() {
    f32x4 z; z[0]=0.f; z[1]=0.f; z[2]=0.f; z[3]=0.f; return z;
}
__device__ __forceinline__ f32x16 zero16() {
    f32x16 z;
#pragma unroll
    for (int i = 0; i < 16; ++i) z[i] = 0.f;
    return z;
}

__global__ void ws_diag(float* out, float code) { out[0] = code; }

// ---------------------------------------------------------------------------
// Kernel 1: QKV projection, MFMA 16x16x32 bf16.
// Block tile 128m x 192n (one head), grid (32 mt, 16 h), 4 waves = 2x2,
// wave tile 64m x 96n (4x6 16-tiles). A=x fp32->bf16; B=Wqkv staged
// transposed [n][k] (coalesced column reads). Outputs bf16 [B,H,N,64].
// ---------------------------------------------------------------------------
__global__ __launch_bounds__(256) void qkv_mfma(
    const float* __restrict__ x, const float* __restrict__ W,
    const float* __restrict__ bias,
    u16* __restrict__ kbuf, u16* __restrict__ qbuf, u16* __restrict__ vbuf)
{
    const int mt = blockIdx.x;   // 0..31
    const int h  = blockIdx.y;   // 0..15
    const int tid = threadIdx.x;
    const int lane = tid & 63, wid = tid >> 6;
    const int wy = wid >> 1, wx = wid & 1;
    const int quad = lane >> 4, l15 = lane & 15;

    __shared__ u16 As[128][72];  // [m][k], stride 144B (16B-aligned, 2-way banks)
    __shared__ u16 Bs[192][72];  // [n][k] (W transposed)

    f32x4 acc[4][6];
#pragma unroll
    for (int mi = 0; mi < 4; ++mi)
#pragma unroll
        for (int ni = 0; ni < 6; ++ni) acc[mi][ni] = zero4();

    const float* xb = x + (size_t)mt * 128 * Ee;
    const float* wb = W + (size_t)h * Ee * 192;
    const int arow = tid >> 1, akh = (tid & 1) * 32;

    for (int k0 = 0; k0 < Ee; k0 += 64) {
        __syncthreads();
        // A stage: 128x64 fp32 -> bf16
        {
            const float* asrc = xb + (size_t)arow * Ee + k0 + akh;
#pragma unroll
            for (int g = 0; g < 4; ++g) {
                float4 f0 = ((const float4*)asrc)[2 * g];
                float4 f1 = ((const float4*)asrc)[2 * g + 1];
                uint4 pk;
                pk.x = pack2(f0.x, f0.y); pk.y = pack2(f0.z, f0.w);
                pk.z = pack2(f1.x, f1.y); pk.w = pack2(f1.z, f1.w);
                *(uint4*)&As[arow][akh + 8 * g] = pk;
            }
        }
        // B stage: 64k x 192n fp32, transposed into Bs[n][k]. 768 chunks of 16k.
        for (int c = tid; c < 768; c += 256) {
            int n = c % 192;
            int g = c / 192;           // k-group of 16
            const float* bsrc = wb + (size_t)(k0 + g * 16) * 192 + n;
            u32 wv[8];
#pragma unroll
            for (int q = 0; q < 8; ++q)
                wv[q] = pack2(bsrc[(2 * q) * 192], bsrc[(2 * q + 1) * 192]);
            *(uint4*)&Bs[n][g * 16]     = make_uint4(wv[0], wv[1], wv[2], wv[3]);
            *(uint4*)&Bs[n][g * 16 + 8] = make_uint4(wv[4], wv[5], wv[6], wv[7]);
        }
        __syncthreads();
#pragma unroll
        for (int kk0 = 0; kk0 < 64; kk0 += 32) {
            bf16x8 af[4], bfr[6];
#pragma unroll
            for (int mi = 0; mi < 4; ++mi)
                af[mi] = ld_frag(&As[wy * 64 + mi * 16 + l15][kk0 + quad * 8]);
#pragma unroll
            for (int ni = 0; ni < 6; ++ni)
                bfr[ni] = ld_frag(&Bs[wx * 96 + ni * 16 + l15][kk0 + quad * 8]);
#pragma unroll
            for (int mi = 0; mi < 4; ++mi)
#pragma unroll
                for (int ni = 0; ni < 6; ++ni)
                    acc[mi][ni] = __builtin_amdgcn_mfma_f32_16x16x32_bf16(
                        af[mi], bfr[ni], acc[mi][ni], 0, 0, 0);
        }
    }

    // epilogue: C layout col=lane&15, row=quad*4+reg. Split 192 = k|q|v.
#pragma unroll
    for (int ni = 0; ni < 6; ++ni) {
        int col = wx * 96 + ni * 16 + l15;   // 0..191
        int ft = col >> 6, d = col & 63;
        u16* dst = (ft == 0) ? kbuf : (ft == 1) ? qbuf : vbuf;
        float bv = bias[h * 192 + col];
#pragma unroll
        for (int mi = 0; mi < 4; ++mi)
#pragma unroll
            for (int r = 0; r < 4; ++r) {
                int gm = mt * 128 + wy * 64 + mi * 16 + quad * 4 + r;
                int bb = gm >> 11, n = gm & (Nn - 1);
                dst[(((size_t)(bb * Hh + h)) * Nn + n) * HD + d] =
                    f2bf(acc[mi][ni][r] + bv);
            }
    }
}

// ---------------------------------------------------------------------------
// Kernel 2: causal flash attention, MFMA 32x32x16 bf16.
// Grid (16 qtiles of 128, 32 bh), 4 waves, wave = 32q x 64k (softmax
// wave-local). Q-frags persistent in regs; K LDS [key][d]; V transposed
// LDS [d][key]; P LDS round-trip [q][key]. LDS = 36 KB.
// ---------------------------------------------------------------------------
__global__ __launch_bounds__(256) void attn_mfma(
    const u16* __restrict__ qbuf, const u16* __restrict__ kbuf,
    const u16* __restrict__ vbuf, u16* __restrict__ sabuf)
{
    const int qt = blockIdx.x;   // 0..15
    const int bh = blockIdx.y;   // 0..31
    const int b = bh >> 4, h = bh & 15;
    const int tid = threadIdx.x;
    const int lane = tid & 63, wid = tid >> 6;
    const int l31 = lane & 31, half = lane >> 5;
    const int khalf = half * 8;

    __shared__ u16 Ks[64][72];   // [key][d]
    __shared__ u16 Vt[64][72];   // [d][key]
    __shared__ u16 Ps[128][72];  // [q][key]

    const u16* qb = qbuf + ((size_t)bh * Nn + qt * 128) * HD;
    const u16* kb = kbuf + (size_t)bh * Nn * HD;
    const u16* vb = vbuf + (size_t)bh * Nn * HD;

    // persistent Q A-frags: rows wid*32 + l31, k chunks of 16
    bf16x8 qf[4];
    const int qrow_l = wid * 32 + l31;
#pragma unroll
    for (int kc = 0; kc < 4; ++kc)
        qf[kc] = __builtin_bit_cast(bf16x8,
            *(const uint4*)(qb + (size_t)qrow_l * HD + kc * 16 + khalf));

    f32x16 oacc[2];
    oacc[0] = zero16(); oacc[1] = zero16();
    float m_i[16], l_i[16];
#pragma unroll
    for (int r = 0; r < 16; ++r) { m_i[r] = -3e38f; l_i[r] = 0.f; }

    const int skey = tid >> 2, sdq = (tid & 3) * 16;
    const int nkt = 2 * (qt + 1);
    const int row_base = qt * 128 + wid * 32;

    for (int kt = 0; kt < nkt; ++kt) {
        __syncthreads();  // prev PV reads of Ks/Vt/Ps done
        {
            const u16* ksrc = kb + ((size_t)(kt * 64 + skey)) * HD + sdq;
            *(uint4*)&Ks[skey][sdq]     = *(const uint4*)(ksrc);
            *(uint4*)&Ks[skey][sdq + 8] = *(const uint4*)(ksrc + 8);
            const u16* vsrc = vb + ((size_t)(kt * 64 + skey)) * HD + sdq;
            uint4 v0 = *(const uint4*)(vsrc);
            uint4 v1 = *(const uint4*)(vsrc + 8);
            u32 wv[8] = {v0.x, v0.y, v0.z, v0.w, v1.x, v1.y, v1.z, v1.w};
#pragma unroll
            for (int q = 0; q < 8; ++q) {
                Vt[sdq + 2 * q][skey]     = (u16)(wv[q] & 0xFFFFu);
                Vt[sdq + 2 * q + 1][skey] = (u16)(wv[q] >> 16);
            }
        }
        __syncthreads();

        const bool fullmask = (kt * 64 >= row_base + 32);  // wave all-masked
        f32x16 s[2];
        if (!fullmask) {
            // S = Q K^T (2 col tiles of 32 keys)
#pragma unroll
            for (int ct = 0; ct < 2; ++ct) {
                f32x16 a = zero16();
#pragma unroll
                for (int kc = 0; kc < 4; ++kc) {
                    bf16x8 bf = ld_frag(&Ks[ct * 32 + l31][kc * 16 + khalf]);
                    a = __builtin_amdgcn_mfma_f32_32x32x16_bf16(qf[kc], bf, a, 0, 0, 0);
                }
                s[ct] = a;
            }
            const bool needmask = (kt * 64 + 63 > row_base);
#pragma unroll
            for (int ct = 0; ct < 2; ++ct) {
                int key = kt * 64 + ct * 32 + l31;
#pragma unroll
                for (int r = 0; r < 16; ++r) {
                    int row_l = (r & 3) + 8 * (r >> 2) + 4 * half;
                    float v = s[ct][r] * 0.125f;
                    if (needmask && key > row_base + row_l) v = -3e38f;
                    s[ct][r] = v;
                }
            }
            // online softmax (rows shared by 32 lanes of same half)
            float mnew[16];
#pragma unroll
            for (int r = 0; r < 16; ++r) mnew[r] = fmaxf(s[0][r], s[1][r]);
#pragma unroll
            for (int msk = 1; msk <= 16; msk <<= 1)
#pragma unroll
                for (int r = 0; r < 16; ++r)
                    mnew[r] = fmaxf(mnew[r], __shfl_xor(mnew[r], msk));
            float alpha[16], rsum[16];
#pragma unroll
            for (int r = 0; r < 16; ++r) {
                float mn = fmaxf(m_i[r], mnew[r]);
                alpha[r] = __expf(m_i[r] - mn);
                m_i[r] = mn;
                float p0 = __expf(s[0][r] - mn);
                float p1 = __expf(s[1][r] - mn);
                s[0][r] = p0; s[1][r] = p1;
                rsum[r] = p0 + p1;
            }
#pragma unroll
            for (int msk = 1; msk <= 16; msk <<= 1)
#pragma unroll
                for (int r = 0; r < 16; ++r)
                    rsum[r] += __shfl_xor(rsum[r], msk);
#pragma unroll
            for (int r = 0; r < 16; ++r) {
                l_i[r] = l_i[r] * alpha[r] + rsum[r];
                oacc[0][r] *= alpha[r];
                oacc[1][r] *= alpha[r];
            }
            // P -> LDS (A-layout source rows)
#pragma unroll
            for (int ct = 0; ct < 2; ++ct)
#pragma unroll
                for (int r = 0; r < 16; ++r) {
                    int row_l = (r & 3) + 8 * (r >> 2) + 4 * half;
                    Ps[wid * 32 + row_l][ct * 32 + l31] = f2bf(s[ct][r]);
                }
        }
        __syncthreads();
        if (!fullmask) {
            bf16x8 pf[4];
#pragma unroll
            for (int kc = 0; kc < 4; ++kc)
                pf[kc] = ld_frag(&Ps[wid * 32 + l31][kc * 16 + khalf]);
#pragma unroll
            for (int dt = 0; dt < 2; ++dt)
#pragma unroll
                for (int kc = 0; kc < 4; ++kc) {
                    bf16x8 vf = ld_frag(&Vt[dt * 32 + l31][kc * 16 + khalf]);
                    oacc[dt] = __builtin_amdgcn_mfma_f32_32x32x16_bf16(
                        pf[kc], vf, oacc[dt], 0, 0, 0);
                }
        }
    }

    float inv[16];
#pragma unroll
    for (int r = 0; r < 16; ++r) inv[r] = 1.f / l_i[r];
#pragma unroll
    for (int dt = 0; dt < 2; ++dt)
#pragma unroll
        for (int r = 0; r < 16; ++r) {
            int row_l = (r & 3) + 8 * (r >> 2) + 4 * half;
            int token = qt * 128 + wid * 32 + row_l;
            int col = h * 64 + dt * 32 + l31;
            sabuf[((size_t)(b * Nn + token)) * Ee + col] = f2bf(oacc[dt][r] * inv[r]);
        }
}

// ---------------------------------------------------------------------------
// Kernel 3: output projection, MFMA 32x32x16 bf16.
// Block 128m x 64n, grid (32, 16), wave = 32m x 64n (2 col tiles).
// A = sabuf bf16; B = Wout fp32 staged transposed [n][k]; out fp32.
// ---------------------------------------------------------------------------
__global__ __launch_bounds__(256) void out_mfma(
    const u16* __restrict__ A, const float* __restrict__ W,
    const float* __restrict__ bias, float* __restrict__ out)
{
    const int mt = blockIdx.x;  // 0..31
    const int nt = blockIdx.y;  // 0..15
    const int tid = threadIdx.x;
    const int lane = tid & 63, wid = tid >> 6;
    const int l31 = lane & 31, khalf = (lane >> 5) * 8;

    __shared__ u16 As[128][72];  // [m][k]
    __shared__ u16 Bs[64][72];   // [n][k]

    f32x16 acc[2];
    acc[0] = zero16(); acc[1] = zero16();

    const u16* ab = A + (size_t)mt * 128 * Ee;
    const int arow = tid >> 1, akh = (tid & 1) * 32;
    const int bn = tid & 63, bg = tid >> 6;  // n, k-group of 16

    for (int k0 = 0; k0 < Ee; k0 += 64) {
        __syncthreads();
        {
            const u16* asrc = ab + (size_t)arow * Ee + k0 + akh;
#pragma unroll
            for (int j = 0; j < 4; ++j)
                *(uint4*)&As[arow][akh + 8 * j] = *(const uint4*)(asrc + 8 * j);
        }
        {
            const float* bsrc = W + (size_t)(k0 + bg * 16) * Ee + nt * 64 + bn;
            u32 wv[8];
#pragma unroll
            for (int q = 0; q < 8; ++q)
                wv[q] = pack2(bsrc[(2 * q) * Ee], bsrc[(2 * q + 1) * Ee]);
            *(uint4*)&Bs[bn][bg * 16]     = make_uint4(wv[0], wv[1], wv[2], wv[3]);
            *(uint4*)&Bs[bn][bg * 16 + 8] = make_uint4(wv[4], wv[5], wv[6], wv[7]);
        }
        __syncthreads();
#pragma unroll
        for (int kc = 0; kc < 4; ++kc) {
            bf16x8 af = ld_frag(&As[wid * 32 + l31][kc * 16 + khalf]);
#pragma unroll
            for (int ct = 0; ct < 2; ++ct) {
                bf16x8 bf = ld_frag(&Bs[ct * 32 + l31][kc * 16 + khalf]);
                acc[ct] = __builtin_amdgcn_mfma_f32_32x32x16_bf16(af, bf, acc[ct], 0, 0, 0);
            }
        }
    }

#pragma unroll
    for (int ct = 0; ct < 2; ++ct) {
        int col = nt * 64 + ct * 32 + l31;
        float bv = bias[col];
#pragma unroll
        for (int r = 0; r < 16; ++r) {
            int row_l = (r & 3) + 8 * (r >> 2) + 4 * (lane >> 5);
            int gm = mt * 128 + wid * 32 + row_l;
            out[(size_t)gm * Ee + col] = acc[ct][r] + bv;
        }
    }
}

// ---------------------------------------------------------------------------
extern "C" void kernel_launch(void* const* d_in, const int* in_sizes, int n_in,
                              void* d_out, int out_size, void* d_ws, size_t ws_size,
                              hipStream_t stream) {
    const float* x    = (const float*)d_in[0];  // [2,2048,1024] f32
    const float* Wqkv = (const float*)d_in[1];  // [16,1024,192] f32
    const float* bqkv = (const float*)d_in[2];  // [16,192] f32
    const float* Wout = (const float*)d_in[3];  // [1024,1024] f32
    const float* bout = (const float*)d_in[4];  // [1024] f32
    float* out = (float*)d_out;                 // [2,2048,1024] f32

    const size_t SZ = (size_t)Bz * Hh * Nn * HD;        // 4,194,304 elems
    const size_t NSA = (size_t)Bz * Nn * Ee;            // 4,194,304 elems
    const size_t NEED = (3 * SZ + NSA) * sizeof(u16);   // 32 MiB

    if (ws_size < NEED) {
        ws_diag<<<1, 1, 0, stream>>>(out, 20000.0f + (float)(ws_size >> 20));
        return;
    }

    u16* ws = (u16*)d_ws;
    u16* kbuf  = ws;
    u16* qbuf  = ws + SZ;
    u16* vbuf  = ws + 2 * SZ;
    u16* sabuf = ws + 3 * SZ;

    qkv_mfma<<<dim3(32, 16), 256, 0, stream>>>(x, Wqkv, bqkv, kbuf, qbuf, vbuf);
    attn_mfma<<<dim3(16, 32), 256, 0, stream>>>(qbuf, kbuf, vbuf, sabuf);
    out_mfma<<<dim3(32, 16), 256, 0, stream>>>(sabuf, Wout, bout, out);
}

// Round 7
// 283.505 us; speedup vs baseline: 4.2237x; 1.3895x over previous
//
#include <hip/hip_runtime.h>
#include <hip/hip_bf16.h>

// B=2, N=2048, E=1024, H=16, HD=64. Inputs fp32, output fp32.
// ws (32 MiB): kbuf qbuf vbuf sabuf (bf16, 8 MB each).
// Wqkv_t (6 MB bf16) lives in sabuf region until attn; Wout_t (2 MB) in kbuf after attn.
#define Bz 2
#define Nn 2048
#define Ee 1024
#define Hh 16
#define HD 64

typedef unsigned short u16;
typedef unsigned int u32;

typedef __bf16 bf16x8 __attribute__((ext_vector_type(8)));
typedef float f32x4 __attribute__((ext_vector_type(4)));

__device__ __forceinline__ float bf2f(u16 u) {
    u32 v = ((u32)u) << 16;
    return __builtin_bit_cast(float, v);
}
__device__ __forceinline__ u16 f2bf(float f) {
    u32 i = __builtin_bit_cast(u32, f);
    u32 r = (i + 0x7FFFu + ((i >> 16) & 1u)) >> 16;  // RNE
    return (u16)r;
}
__device__ __forceinline__ u32 pack2(float a, float b) {
    return (u32)f2bf(a) | ((u32)f2bf(b) << 16);
}
__device__ __forceinline__ bf16x8 ld_frag(const u16* p) {
    return __builtin_bit_cast(bf16x8, *(const uint4*)p);
}
__device__ __forceinline__ f32x4 zero4() {
    f32x4 z; z[0]=0.f; z[1]=0.f; z[2]=0.f; z[3]=0.f; return z;
}

__global__ void ws_diag(float* out, float code) { out[0] = code; }

// ---------------------------------------------------------------------------
// Transpose f32 [R][C] -> bf16 [C][R], per z-slice. R,C multiples of 64.
// ---------------------------------------------------------------------------
__global__ __launch_bounds__(256) void transpose_f32_bf16(
    const float* __restrict__ src, u16* __restrict__ dst, int R, int C)
{
    const int r0 = blockIdx.x * 64, c0 = blockIdx.y * 64;
    const size_t zoff = (size_t)blockIdx.z * R * C;
    src += zoff; dst += zoff;
    const int tid = threadIdx.x;

    __shared__ float T[64][65];
    {
        int tr = tid >> 2, tc = (tid & 3) * 16;
        const float* s = src + (size_t)(r0 + tr) * C + c0 + tc;
#pragma unroll
        for (int j = 0; j < 4; ++j) {
            float4 v = ((const float4*)s)[j];
            T[tr][tc + 4 * j + 0] = v.x; T[tr][tc + 4 * j + 1] = v.y;
            T[tr][tc + 4 * j + 2] = v.z; T[tr][tc + 4 * j + 3] = v.w;
        }
    }
    __syncthreads();
    {
        int cc = tid >> 2, rr = (tid & 3) * 16;
        u16* d = dst + (size_t)(c0 + cc) * R + r0 + rr;
        u32 w[8];
#pragma unroll
        for (int i = 0; i < 8; ++i)
            w[i] = pack2(T[rr + 2 * i][cc], T[rr + 2 * i + 1][cc]);
        *(uint4*)(d)     = make_uint4(w[0], w[1], w[2], w[3]);
        *(uint4*)(d + 8) = make_uint4(w[4], w[5], w[6], w[7]);
    }
}

// ---------------------------------------------------------------------------
// Kernel 1: QKV projection, MFMA 16x16x32.
// A = x fp32 -> bf16 inline; B = Wqkv_t bf16 [h][192 n][1024 k] (contiguous).
// Block 128m x 192n (one head), 4 waves 2x2, wave 64m x 96n.
// ---------------------------------------------------------------------------
__global__ __launch_bounds__(256) void qkv_mfma(
    const float* __restrict__ x, const u16* __restrict__ Wt,
    const float* __restrict__ bias,
    u16* __restrict__ kbuf, u16* __restrict__ qbuf, u16* __restrict__ vbuf)
{
    const int mt = blockIdx.x;   // 0..31
    const int h  = blockIdx.y;   // 0..15
    const int tid = threadIdx.x;
    const int lane = tid & 63, wid = tid >> 6;
    const int wy = wid >> 1, wx = wid & 1;
    const int quad = lane >> 4, l15 = lane & 15;

    __shared__ u16 As[128][72];  // [m][k]
    __shared__ u16 Bs[192][72];  // [n][k]

    f32x4 acc[4][6];
#pragma unroll
    for (int mi = 0; mi < 4; ++mi)
#pragma unroll
        for (int ni = 0; ni < 6; ++ni) acc[mi][ni] = zero4();

    const float* xb = x + (size_t)mt * 128 * Ee;
    const u16* wtb = Wt + (size_t)h * 192 * 1024;
    const int arow = tid >> 1, akh = (tid & 1) * 32;

    for (int k0 = 0; k0 < Ee; k0 += 64) {
        __syncthreads();
        {
            const float* asrc = xb + (size_t)arow * Ee + k0 + akh;
#pragma unroll
            for (int g = 0; g < 4; ++g) {
                float4 f0 = ((const float4*)asrc)[2 * g];
                float4 f1 = ((const float4*)asrc)[2 * g + 1];
                uint4 pk;
                pk.x = pack2(f0.x, f0.y); pk.y = pack2(f0.z, f0.w);
                pk.z = pack2(f1.x, f1.y); pk.w = pack2(f1.z, f1.w);
                *(uint4*)&As[arow][akh + 8 * g] = pk;
            }
        }
#pragma unroll
        for (int c = tid; c < 1536; c += 256) {
            int row = c >> 3, col8 = (c & 7) * 8;
            *(uint4*)&Bs[row][col8] =
                *(const uint4*)(wtb + (size_t)row * 1024 + k0 + col8);
        }
        __syncthreads();
#pragma unroll
        for (int kk0 = 0; kk0 < 64; kk0 += 32) {
            bf16x8 af[4], bfr[6];
#pragma unroll
            for (int mi = 0; mi < 4; ++mi)
                af[mi] = ld_frag(&As[wy * 64 + mi * 16 + l15][kk0 + quad * 8]);
#pragma unroll
            for (int ni = 0; ni < 6; ++ni)
                bfr[ni] = ld_frag(&Bs[wx * 96 + ni * 16 + l15][kk0 + quad * 8]);
#pragma unroll
            for (int mi = 0; mi < 4; ++mi)
#pragma unroll
                for (int ni = 0; ni < 6; ++ni)
                    acc[mi][ni] = __builtin_amdgcn_mfma_f32_16x16x32_bf16(
                        af[mi], bfr[ni], acc[mi][ni], 0, 0, 0);
        }
    }

#pragma unroll
    for (int ni = 0; ni < 6; ++ni) {
        int col = wx * 96 + ni * 16 + l15;   // 0..191
        int ft = col >> 6, d = col & 63;
        u16* dst = (ft == 0) ? kbuf : (ft == 1) ? qbuf : vbuf;
        float bv = bias[h * 192 + col];
#pragma unroll
        for (int mi = 0; mi < 4; ++mi)
#pragma unroll
            for (int r = 0; r < 4; ++r) {
                int gm = mt * 128 + wy * 64 + mi * 16 + quad * 4 + r;
                int bb = gm >> 11, n = gm & (Nn - 1);
                dst[(((size_t)(bb * Hh + h)) * Nn + n) * HD + d] =
                    f2bf(acc[mi][ni][r] + bv);
            }
    }
}

// ---------------------------------------------------------------------------
// Kernel 2: causal flash attention, transposed-S scheme, MFMA 16x16x32.
// Block = paired q-tiles (p, 31-p) of 64 rows -> 33 k-iters/block, uniform.
// 4 waves x 16 q-rows. S^T = mfma(K, Q): lane owns one q entirely ->
// softmax = in-lane + 2 shuffles. P stays in registers: B-frags built via
// dest-side-selected shuffles (source-side select was the R6 bug).
// O^T = mfma(V^T, P). LDS = Ks + Vt = 18.4 KB.
// ---------------------------------------------------------------------------
__global__ __launch_bounds__(256) void attn2(
    const u16* __restrict__ qbuf, const u16* __restrict__ kbuf,
    const u16* __restrict__ vbuf, u16* __restrict__ sabuf)
{
    const int p  = blockIdx.x;   // 0..15 (pair index)
    const int bh = blockIdx.y;   // 0..31
    const int b = bh >> 4, h = bh & 15;
    const int tid = threadIdx.x;
    const int lane = tid & 63, wid = tid >> 6;
    const int l15 = lane & 15, quad = lane >> 4;

    __shared__ u16 Ks[64][72];   // [key][d]
    __shared__ u16 Vt[64][72];   // [d][key]

    const u16* qb = qbuf + (size_t)bh * Nn * HD;
    const u16* kb = kbuf + (size_t)bh * Nn * HD;
    const u16* vb = vbuf + (size_t)bh * Nn * HD;

    // K staging: full rows, 4 lanes/row
    const int skey = tid >> 2, sdq = (tid & 3) * 16;
    // V staging: lane-per-key (LDS bank spread over all 32 banks)
    const int vkey = tid & 63, vd = (tid >> 6) * 16;

    // P B-frag shuffle sources: dest (quad,l15) pulls from lanes
    // src0 = l15 + (quad&1)*32 and src0+16; selects even/odd-t by quad>=2.
    const int src0 = l15 + (quad & 1) * 32;
    const bool qhi = quad >= 2;

    for (int hx = 0; hx < 2; ++hx) {
        const int qt = hx ? (31 - p) : p;
        const int nkt = qt + 1;
        const int qrow = qt * 64 + wid * 16 + l15;  // this lane's q row

        bf16x8 qf[2];
#pragma unroll
        for (int st = 0; st < 2; ++st)
            qf[st] = __builtin_bit_cast(bf16x8,
                *(const uint4*)(qb + (size_t)qrow * HD + st * 32 + quad * 8));

        f32x4 oacc[4];
#pragma unroll
        for (int dt = 0; dt < 4; ++dt) oacc[dt] = zero4();
        float m_i = -3e38f, l_i = 0.f;

        for (int kt = 0; kt < nkt; ++kt) {
            __syncthreads();  // prior MFMA reads of Ks/Vt done
            {
                const u16* ksrc = kb + (size_t)(kt * 64 + skey) * HD + sdq;
                *(uint4*)&Ks[skey][sdq]     = *(const uint4*)(ksrc);
                *(uint4*)&Ks[skey][sdq + 8] = *(const uint4*)(ksrc + 8);
                const u16* vsrc = vb + (size_t)(kt * 64 + vkey) * HD + vd;
                uint4 a = *(const uint4*)(vsrc);
                uint4 c = *(const uint4*)(vsrc + 8);
                u32 w[8] = {a.x, a.y, a.z, a.w, c.x, c.y, c.z, c.w};
#pragma unroll
                for (int j = 0; j < 8; ++j) {
                    Vt[vd + 2 * j][vkey]     = (u16)(w[j] & 0xFFFFu);
                    Vt[vd + 2 * j + 1][vkey] = (u16)(w[j] >> 16);
                }
            }
            __syncthreads();

            // S^T[key][q]: 4 key-tiles of 16
            f32x4 s[4];
#pragma unroll
            for (int t = 0; t < 4; ++t) {
                f32x4 a = zero4();
#pragma unroll
                for (int st = 0; st < 2; ++st) {
                    bf16x8 kf = ld_frag(&Ks[t * 16 + l15][st * 32 + quad * 8]);
                    a = __builtin_amdgcn_mfma_f32_16x16x32_bf16(kf, qf[st], a, 0, 0, 0);
                }
                s[t] = a;
            }

            // scale + causal mask (only the diagonal k-tile needs masking)
            const bool dn = (kt == qt);
#pragma unroll
            for (int t = 0; t < 4; ++t)
#pragma unroll
                for (int r = 0; r < 4; ++r) {
                    int key = kt * 64 + t * 16 + quad * 4 + r;
                    float v = s[t][r] * 0.125f;
                    if (dn && key > qrow) v = -3e38f;
                    s[t][r] = v;
                }

            // online softmax: in-lane over 16, cross-quad via 2 shuffles
            float mx = s[0][0];
#pragma unroll
            for (int t = 0; t < 4; ++t)
#pragma unroll
                for (int r = 0; r < 4; ++r) mx = fmaxf(mx, s[t][r]);
            mx = fmaxf(mx, __shfl_xor(mx, 16));
            mx = fmaxf(mx, __shfl_xor(mx, 32));
            float mn = fmaxf(m_i, mx);
            float alpha = __expf(m_i - mn);
            m_i = mn;
            float rs = 0.f;
#pragma unroll
            for (int t = 0; t < 4; ++t)
#pragma unroll
                for (int r = 0; r < 4; ++r) {
                    float e = __expf(s[t][r] - mn);
                    s[t][r] = e;
                    rs += e;
                }
            rs += __shfl_xor(rs, 16);
            rs += __shfl_xor(rs, 32);
            l_i = l_i * alpha + rs;
#pragma unroll
            for (int dt = 0; dt < 4; ++dt)
#pragma unroll
                for (int r = 0; r < 4; ++r) oacc[dt][r] *= alpha;

            // pack P (bf16 pairs); build B-frags: pull BOTH t-parity
            // candidates, select with DEST lane's qhi (fix for R6 bug).
            u32 pk[4][2];
#pragma unroll
            for (int t = 0; t < 4; ++t) {
                pk[t][0] = pack2(s[t][0], s[t][1]);
                pk[t][1] = pack2(s[t][2], s[t][3]);
            }
#pragma unroll
            for (int st = 0; st < 2; ++st) {
                u32 e0 = pk[2 * st][0],     e1 = pk[2 * st][1];
                u32 o0 = pk[2 * st + 1][0], o1 = pk[2 * st + 1][1];
                u32 A0 = __shfl(e0, src0),      B0 = __shfl(o0, src0);
                u32 A1 = __shfl(e1, src0),      B1 = __shfl(o1, src0);
                u32 A2 = __shfl(e0, src0 + 16), B2 = __shfl(o0, src0 + 16);
                u32 A3 = __shfl(e1, src0 + 16), B3 = __shfl(o1, src0 + 16);
                u32 U0 = qhi ? B0 : A0;
                u32 U1 = qhi ? B1 : A1;
                u32 U2 = qhi ? B2 : A2;
                u32 U3 = qhi ? B3 : A3;
                bf16x8 pf = __builtin_bit_cast(bf16x8, make_uint4(U0, U1, U2, U3));
#pragma unroll
                for (int dt = 0; dt < 4; ++dt) {
                    bf16x8 vf = ld_frag(&Vt[dt * 16 + l15][st * 32 + quad * 8]);
                    oacc[dt] = __builtin_amdgcn_mfma_f32_16x16x32_bf16(
                        vf, pf, oacc[dt], 0, 0, 0);
                }
            }
        }

        // epilogue: O^T C-layout col=q(lane), row=d(quad*4+r)
        float inv = 1.f / l_i;
#pragma unroll
        for (int dt = 0; dt < 4; ++dt) {
            ushort4 ov;
            ov.x = f2bf(oacc[dt][0] * inv);
            ov.y = f2bf(oacc[dt][1] * inv);
            ov.z = f2bf(oacc[dt][2] * inv);
            ov.w = f2bf(oacc[dt][3] * inv);
            *(ushort4*)&sabuf[((size_t)(b * Nn + qrow)) * Ee + h * 64 +
                              dt * 16 + quad * 4] = ov;
        }
    }
}

// ---------------------------------------------------------------------------
// Kernel 3: output projection, MFMA 32x32x16.
// A = sabuf bf16; B = Wout_t bf16 [n][k] contiguous; out fp32.
// ---------------------------------------------------------------------------
typedef float f32x16 __attribute__((ext_vector_type(16)));
__device__ __forceinline__ f32x16 zero16() {
    f32x16 z;
#pragma unroll
    for (int i = 0; i < 16; ++i) z[i] = 0.f;
    return z;
}

__global__ __launch_bounds__(256) void out_mfma(
    const u16* __restrict__ A, const u16* __restrict__ Wt,
    const float* __restrict__ bias, float* __restrict__ out)
{
    const int mt = blockIdx.x;  // 0..31
    const int nt = blockIdx.y;  // 0..15
    const int tid = threadIdx.x;
    const int lane = tid & 63, wid = tid >> 6;
    const int l31 = lane & 31, khalf = (lane >> 5) * 8;

    __shared__ u16 As[128][72];
    __shared__ u16 Bs[64][72];

    f32x16 acc[2];
    acc[0] = zero16(); acc[1] = zero16();

    const u16* ab = A + (size_t)mt * 128 * Ee;
    const int arow = tid >> 1, akh = (tid & 1) * 32;
    const int brow = tid >> 2, bc = (tid & 3) * 16;

    for (int k0 = 0; k0 < Ee; k0 += 64) {
        __syncthreads();
        {
            const u16* asrc = ab + (size_t)arow * Ee + k0 + akh;
#pragma unroll
            for (int j = 0; j < 4; ++j)
                *(uint4*)&As[arow][akh + 8 * j] = *(const uint4*)(asrc + 8 * j);
            const u16* bsrc = Wt + (size_t)(nt * 64 + brow) * 1024 + k0 + bc;
            *(uint4*)&Bs[brow][bc]     = *(const uint4*)(bsrc);
            *(uint4*)&Bs[brow][bc + 8] = *(const uint4*)(bsrc + 8);
        }
        __syncthreads();
#pragma unroll
        for (int kc = 0; kc < 4; ++kc) {
            bf16x8 af = ld_frag(&As[wid * 32 + l31][kc * 16 + khalf]);
#pragma unroll
            for (int ct = 0; ct < 2; ++ct) {
                bf16x8 bf = ld_frag(&Bs[ct * 32 + l31][kc * 16 + khalf]);
                acc[ct] = __builtin_amdgcn_mfma_f32_32x32x16_bf16(af, bf, acc[ct], 0, 0, 0);
            }
        }
    }

#pragma unroll
    for (int ct = 0; ct < 2; ++ct) {
        int col = nt * 64 + ct * 32 + l31;
        float bv = bias[col];
#pragma unroll
        for (int r = 0; r < 16; ++r) {
            int row_l = (r & 3) + 8 * (r >> 2) + 4 * (lane >> 5);
            int gm = mt * 128 + wid * 32 + row_l;
            out[(size_t)gm * Ee + col] = acc[ct][r] + bv;
        }
    }
}

// ---------------------------------------------------------------------------
extern "C" void kernel_launch(void* const* d_in, const int* in_sizes, int n_in,
                              void* d_out, int out_size, void* d_ws, size_t ws_size,
                              hipStream_t stream) {
    const float* x    = (const float*)d_in[0];  // [2,2048,1024] f32
    const float* Wqkv = (const float*)d_in[1];  // [16,1024,192] f32
    const float* bqkv = (const float*)d_in[2];  // [16,192] f32
    const float* Wout = (const float*)d_in[3];  // [1024,1024] f32
    const float* bout = (const float*)d_in[4];  // [1024] f32
    float* out = (float*)d_out;                 // [2,2048,1024] f32

    const size_t SZ = (size_t)Bz * Hh * Nn * HD;        // 4,194,304 elems
    const size_t NSA = (size_t)Bz * Nn * Ee;            // 4,194,304 elems
    const size_t NEED = (3 * SZ + NSA) * sizeof(u16);   // 32 MiB

    if (ws_size < NEED) {
        ws_diag<<<1, 1, 0, stream>>>(out, 20000.0f + (float)(ws_size >> 20));
        return;
    }

    u16* ws = (u16*)d_ws;
    u16* kbuf  = ws;
    u16* qbuf  = ws + SZ;
    u16* vbuf  = ws + 2 * SZ;
    u16* sabuf = ws + 3 * SZ;
    u16* wqkv_t = sabuf;  // 16*192*1024 = 3.1M elems (6 MB) in dead sa region
    u16* wout_t = kbuf;   // 1M elems (2 MB) in dead k region (after attn)

    // Wqkv [h][1024 k][192 n] f32 -> [h][192 n][1024 k] bf16
    transpose_f32_bf16<<<dim3(16, 3, 16), 256, 0, stream>>>(Wqkv, wqkv_t, 1024, 192);
    qkv_mfma<<<dim3(32, 16), 256, 0, stream>>>(x, wqkv_t, bqkv, kbuf, qbuf, vbuf);
    attn2<<<dim3(16, 32), 256, 0, stream>>>(qbuf, kbuf, vbuf, sabuf);
    // Wout [1024 k][1024 n] f32 -> [1024 n][1024 k] bf16 (kbuf now dead)
    transpose_f32_bf16<<<dim3(16, 16, 1), 256, 0, stream>>>(Wout, wout_t, 1024, 1024);
    out_mfma<<<dim3(32, 16), 256, 0, stream>>>(sabuf, wout_t, bout, out);
}

// Round 8
// 208.760 us; speedup vs baseline: 5.7359x; 1.3580x over previous
//
#include <hip/hip_runtime.h>
#include <hip/hip_bf16.h>

// B=2, N=2048, E=1024, H=16, HD=64. Inputs fp32, output fp32.
// ws (32 MiB): kbuf qbuf vbuf sabuf (bf16, 8 MB each).
// Wqkv_t (6 MB bf16) in sabuf region until attn; Wout_t (2 MB) in kbuf after attn.
// x_bf16 (8 MB) lives in d_out (dead scratch until out_mfma overwrites it).
#define Bz 2
#define Nn 2048
#define Ee 1024
#define Hh 16
#define HD 64

typedef unsigned short u16;
typedef unsigned int u32;

typedef __bf16 bf16x8 __attribute__((ext_vector_type(8)));
typedef float f32x4 __attribute__((ext_vector_type(4)));

__device__ __forceinline__ float bf2f(u16 u) {
    u32 v = ((u32)u) << 16;
    return __builtin_bit_cast(float, v);
}
__device__ __forceinline__ u16 f2bf(float f) {
    u32 i = __builtin_bit_cast(u32, f);
    u32 r = (i + 0x7FFFu + ((i >> 16) & 1u)) >> 16;  // RNE
    return (u16)r;
}
__device__ __forceinline__ u32 pack2(float a, float b) {
    return (u32)f2bf(a) | ((u32)f2bf(b) << 16);
}
__device__ __forceinline__ bf16x8 ld_frag(const u16* p) {
    return __builtin_bit_cast(bf16x8, *(const uint4*)p);
}
__device__ __forceinline__ f32x4 zero4() {
    f32x4 z; z[0]=0.f; z[1]=0.f; z[2]=0.f; z[3]=0.f; return z;
}

// async 16B/lane global->LDS DMA; LDS dest = (uniform) l + lane*16.
__device__ __forceinline__ void async_copy16(const u16* g, u16* l) {
    __builtin_amdgcn_global_load_lds(
        (const __attribute__((address_space(1))) u32*)g,
        (__attribute__((address_space(3))) u32*)l, 16, 0, 0);
}

__global__ void ws_diag(float* out, float code) { out[0] = code; }

// ---------------------------------------------------------------------------
// x fp32 [4096*1024] -> bf16 (plain row-major), into d_out scratch.
// ---------------------------------------------------------------------------
__global__ __launch_bounds__(256) void convert_x(
    const float* __restrict__ x, u16* __restrict__ xbf)
{
    size_t idx = ((size_t)blockIdx.x * 256 + threadIdx.x) * 8;
    float4 f0 = *(const float4*)(x + idx);
    float4 f1 = *(const float4*)(x + idx + 4);
    uint4 pk;
    pk.x = pack2(f0.x, f0.y); pk.y = pack2(f0.z, f0.w);
    pk.z = pack2(f1.x, f1.y); pk.w = pack2(f1.z, f1.w);
    *(uint4*)(xbf + idx) = pk;
}

// ---------------------------------------------------------------------------
// Transpose f32 [R][C] -> bf16 [C][R], per z-slice. R,C multiples of 64.
// ---------------------------------------------------------------------------
__global__ __launch_bounds__(256) void transpose_f32_bf16(
    const float* __restrict__ src, u16* __restrict__ dst, int R, int C)
{
    const int r0 = blockIdx.x * 64, c0 = blockIdx.y * 64;
    const size_t zoff = (size_t)blockIdx.z * R * C;
    src += zoff; dst += zoff;
    const int tid = threadIdx.x;

    __shared__ float T[64][65];
    {
        int tr = tid >> 2, tc = (tid & 3) * 16;
        const float* s = src + (size_t)(r0 + tr) * C + c0 + tc;
#pragma unroll
        for (int j = 0; j < 4; ++j) {
            float4 v = ((const float4*)s)[j];
            T[tr][tc + 4 * j + 0] = v.x; T[tr][tc + 4 * j + 1] = v.y;
            T[tr][tc + 4 * j + 2] = v.z; T[tr][tc + 4 * j + 3] = v.w;
        }
    }
    __syncthreads();
    {
        int cc = tid >> 2, rr = (tid & 3) * 16;
        u16* d = dst + (size_t)(c0 + cc) * R + r0 + rr;
        u32 w[8];
#pragma unroll
        for (int i = 0; i < 8; ++i)
            w[i] = pack2(T[rr + 2 * i][cc], T[rr + 2 * i + 1][cc]);
        *(uint4*)(d)     = make_uint4(w[0], w[1], w[2], w[3]);
        *(uint4*)(d + 8) = make_uint4(w[4], w[5], w[6], w[7]);
    }
}

// ---------------------------------------------------------------------------
// Kernel 1 v2: QKV projection, MFMA 16x16x32, async global_load_lds staging.
// A = x_bf16 [4096][1024]; B = Wqkv_t [h][192][1024] bf16.
// Block 64m x 192n, grid (64 mt, 16 h) = 1024 blocks. 4 waves split n:
// wave tile 64m x 48n (4x3 16-tiles). LDS unpadded [row][64] with XOR
// chunk swizzle (applied on the global address side of the DMA).
// ---------------------------------------------------------------------------
__global__ __launch_bounds__(256) void qkv_mfma(
    const u16* __restrict__ xbf, const u16* __restrict__ Wt,
    const float* __restrict__ bias,
    u16* __restrict__ kbuf, u16* __restrict__ qbuf, u16* __restrict__ vbuf)
{
    const int mt = blockIdx.x;   // 0..63
    const int h  = blockIdx.y;   // 0..15
    const int tid = threadIdx.x;
    const int lane = tid & 63, wid = tid >> 6;
    const int quad = lane >> 4, l15 = lane & 15;

    __shared__ u16 As[64 * 64];    // [m][8 chunks of 8 bf16], swizzled
    __shared__ u16 Bs[192 * 64];   // [n][8 chunks], swizzled

    f32x4 acc[4][3];
#pragma unroll
    for (int mi = 0; mi < 4; ++mi)
#pragma unroll
        for (int ni = 0; ni < 3; ++ni) acc[mi][ni] = zero4();

    const u16* xb = xbf + (size_t)mt * 64 * Ee;
    const u16* wtb = Wt + (size_t)h * 192 * 1024;

    // per-lane DMA source descriptors (row, swizzled chunk jj)
    const int arowl = lane >> 3;             // relative row within 8-row group
    const int jj = (lane & 7) ^ arowl;       // swizzled chunk index

    for (int kb = 0; kb < 16; ++kb) {
        __syncthreads();  // prev-iter frag reads done
        // A: 8 KB = 8 x 1KB insts, 2 per wave
#pragma unroll
        for (int i = 0; i < 2; ++i) {
            int rbase = (wid * 2 + i) * 8;
            const u16* g = xb + (size_t)(rbase + arowl) * Ee + kb * 64 + jj * 8;
            async_copy16(g, &As[(wid * 2 + i) * 512]);
        }
        // B: 24 KB = 24 insts, 6 per wave
#pragma unroll
        for (int i = 0; i < 6; ++i) {
            int rbase = (wid * 6 + i) * 8;
            const u16* g = wtb + (size_t)(rbase + arowl) * 1024 + kb * 64 + jj * 8;
            async_copy16(g, &Bs[(wid * 6 + i) * 512]);
        }
        __syncthreads();  // drains vmcnt before barrier

#pragma unroll
        for (int kk0 = 0; kk0 < 2; ++kk0) {  // two K=32 phases
            const int pos = ((kk0 * 4 + quad) ^ (l15 & 7)) * 8;
            bf16x8 af[4], bf[3];
#pragma unroll
            for (int mi = 0; mi < 4; ++mi)
                af[mi] = ld_frag(&As[(mi * 16 + l15) * 64 + pos]);
#pragma unroll
            for (int ni = 0; ni < 3; ++ni)
                bf[ni] = ld_frag(&Bs[(wid * 48 + ni * 16 + l15) * 64 + pos]);
#pragma unroll
            for (int mi = 0; mi < 4; ++mi)
#pragma unroll
                for (int ni = 0; ni < 3; ++ni)
                    acc[mi][ni] = __builtin_amdgcn_mfma_f32_16x16x32_bf16(
                        af[mi], bf[ni], acc[mi][ni], 0, 0, 0);
        }
    }

    // epilogue: C layout col=l15, row=quad*4+r. cols 0..191 = k|q|v.
#pragma unroll
    for (int ni = 0; ni < 3; ++ni) {
        int col = wid * 48 + ni * 16 + l15;   // 0..191
        int ft = col >> 6, d = col & 63;
        u16* dst = (ft == 0) ? kbuf : (ft == 1) ? qbuf : vbuf;
        float bv = bias[h * 192 + col];
#pragma unroll
        for (int mi = 0; mi < 4; ++mi)
#pragma unroll
            for (int r = 0; r < 4; ++r) {
                int gm = mt * 64 + mi * 16 + quad * 4 + r;
                int bb = gm >> 11, n = gm & (Nn - 1);
                dst[(((size_t)(bb * Hh + h)) * Nn + n) * HD + d] =
                    f2bf(acc[mi][ni][r] + bv);
            }
    }
}

// ---------------------------------------------------------------------------
// Kernel 2: causal flash attention, transposed-S scheme, MFMA 16x16x32.
// (unchanged from R7 — known good)
// ---------------------------------------------------------------------------
__global__ __launch_bounds__(256) void attn2(
    const u16* __restrict__ qbuf, const u16* __restrict__ kbuf,
    const u16* __restrict__ vbuf, u16* __restrict__ sabuf)
{
    const int p  = blockIdx.x;   // 0..15 (pair index)
    const int bh = blockIdx.y;   // 0..31
    const int b = bh >> 4, h = bh & 15;
    const int tid = threadIdx.x;
    const int lane = tid & 63, wid = tid >> 6;
    const int l15 = lane & 15, quad = lane >> 4;

    __shared__ u16 Ks[64][72];   // [key][d]
    __shared__ u16 Vt[64][72];   // [d][key]

    const u16* qb = qbuf + (size_t)bh * Nn * HD;
    const u16* kb = kbuf + (size_t)bh * Nn * HD;
    const u16* vb = vbuf + (size_t)bh * Nn * HD;

    const int skey = tid >> 2, sdq = (tid & 3) * 16;
    const int vkey = tid & 63, vd = (tid >> 6) * 16;

    const int src0 = l15 + (quad & 1) * 32;
    const bool qhi = quad >= 2;

    for (int hx = 0; hx < 2; ++hx) {
        const int qt = hx ? (31 - p) : p;
        const int nkt = qt + 1;
        const int qrow = qt * 64 + wid * 16 + l15;

        bf16x8 qf[2];
#pragma unroll
        for (int st = 0; st < 2; ++st)
            qf[st] = __builtin_bit_cast(bf16x8,
                *(const uint4*)(qb + (size_t)qrow * HD + st * 32 + quad * 8));

        f32x4 oacc[4];
#pragma unroll
        for (int dt = 0; dt < 4; ++dt) oacc[dt] = zero4();
        float m_i = -3e38f, l_i = 0.f;

        for (int kt = 0; kt < nkt; ++kt) {
            __syncthreads();
            {
                const u16* ksrc = kb + (size_t)(kt * 64 + skey) * HD + sdq;
                *(uint4*)&Ks[skey][sdq]     = *(const uint4*)(ksrc);
                *(uint4*)&Ks[skey][sdq + 8] = *(const uint4*)(ksrc + 8);
                const u16* vsrc = vb + (size_t)(kt * 64 + vkey) * HD + vd;
                uint4 a = *(const uint4*)(vsrc);
                uint4 c = *(const uint4*)(vsrc + 8);
                u32 w[8] = {a.x, a.y, a.z, a.w, c.x, c.y, c.z, c.w};
#pragma unroll
                for (int j = 0; j < 8; ++j) {
                    Vt[vd + 2 * j][vkey]     = (u16)(w[j] & 0xFFFFu);
                    Vt[vd + 2 * j + 1][vkey] = (u16)(w[j] >> 16);
                }
            }
            __syncthreads();

            f32x4 s[4];
#pragma unroll
            for (int t = 0; t < 4; ++t) {
                f32x4 a = zero4();
#pragma unroll
                for (int st = 0; st < 2; ++st) {
                    bf16x8 kf = ld_frag(&Ks[t * 16 + l15][st * 32 + quad * 8]);
                    a = __builtin_amdgcn_mfma_f32_16x16x32_bf16(kf, qf[st], a, 0, 0, 0);
                }
                s[t] = a;
            }

            const bool dn = (kt == qt);
#pragma unroll
            for (int t = 0; t < 4; ++t)
#pragma unroll
                for (int r = 0; r < 4; ++r) {
                    int key = kt * 64 + t * 16 + quad * 4 + r;
                    float v = s[t][r] * 0.125f;
                    if (dn && key > qrow) v = -3e38f;
                    s[t][r] = v;
                }

            float mx = s[0][0];
#pragma unroll
            for (int t = 0; t < 4; ++t)
#pragma unroll
                for (int r = 0; r < 4; ++r) mx = fmaxf(mx, s[t][r]);
            mx = fmaxf(mx, __shfl_xor(mx, 16));
            mx = fmaxf(mx, __shfl_xor(mx, 32));
            float mn = fmaxf(m_i, mx);
            float alpha = __expf(m_i - mn);
            m_i = mn;
            float rs = 0.f;
#pragma unroll
            for (int t = 0; t < 4; ++t)
#pragma unroll
                for (int r = 0; r < 4; ++r) {
                    float e = __expf(s[t][r] - mn);
                    s[t][r] = e;
                    rs += e;
                }
            rs += __shfl_xor(rs, 16);
            rs += __shfl_xor(rs, 32);
            l_i = l_i * alpha + rs;
#pragma unroll
            for (int dt = 0; dt < 4; ++dt)
#pragma unroll
                for (int r = 0; r < 4; ++r) oacc[dt][r] *= alpha;

            u32 pk[4][2];
#pragma unroll
            for (int t = 0; t < 4; ++t) {
                pk[t][0] = pack2(s[t][0], s[t][1]);
                pk[t][1] = pack2(s[t][2], s[t][3]);
            }
#pragma unroll
            for (int st = 0; st < 2; ++st) {
                u32 e0 = pk[2 * st][0],     e1 = pk[2 * st][1];
                u32 o0 = pk[2 * st + 1][0], o1 = pk[2 * st + 1][1];
                u32 A0 = __shfl(e0, src0),      B0 = __shfl(o0, src0);
                u32 A1 = __shfl(e1, src0),      B1 = __shfl(o1, src0);
                u32 A2 = __shfl(e0, src0 + 16), B2 = __shfl(o0, src0 + 16);
                u32 A3 = __shfl(e1, src0 + 16), B3 = __shfl(o1, src0 + 16);
                u32 U0 = qhi ? B0 : A0;
                u32 U1 = qhi ? B1 : A1;
                u32 U2 = qhi ? B2 : A2;
                u32 U3 = qhi ? B3 : A3;
                bf16x8 pf = __builtin_bit_cast(bf16x8, make_uint4(U0, U1, U2, U3));
#pragma unroll
                for (int dt = 0; dt < 4; ++dt) {
                    bf16x8 vf = ld_frag(&Vt[dt * 16 + l15][st * 32 + quad * 8]);
                    oacc[dt] = __builtin_amdgcn_mfma_f32_16x16x32_bf16(
                        vf, pf, oacc[dt], 0, 0, 0);
                }
            }
        }

        float inv = 1.f / l_i;
#pragma unroll
        for (int dt = 0; dt < 4; ++dt) {
            ushort4 ov;
            ov.x = f2bf(oacc[dt][0] * inv);
            ov.y = f2bf(oacc[dt][1] * inv);
            ov.z = f2bf(oacc[dt][2] * inv);
            ov.w = f2bf(oacc[dt][3] * inv);
            *(ushort4*)&sabuf[((size_t)(b * Nn + qrow)) * Ee + h * 64 +
                              dt * 16 + quad * 4] = ov;
        }
    }
}

// ---------------------------------------------------------------------------
// Kernel 3: output projection, MFMA 32x32x16. (unchanged from R7)
// ---------------------------------------------------------------------------
typedef float f32x16 __attribute__((ext_vector_type(16)));
__device__ __forceinline__ f32x16 zero16() {
    f32x16 z;
#pragma unroll
    for (int i = 0; i < 16; ++i) z[i] = 0.f;
    return z;
}

__global__ __launch_bounds__(256) void out_mfma(
    const u16* __restrict__ A, const u16* __restrict__ Wt,
    const float* __restrict__ bias, float* __restrict__ out)
{
    const int mt = blockIdx.x;  // 0..31
    const int nt = blockIdx.y;  // 0..15
    const int tid = threadIdx.x;
    const int lane = tid & 63, wid = tid >> 6;
    const int l31 = lane & 31, khalf = (lane >> 5) * 8;

    __shared__ u16 As[128][72];
    __shared__ u16 Bs[64][72];

    f32x16 acc[2];
    acc[0] = zero16(); acc[1] = zero16();

    const u16* ab = A + (size_t)mt * 128 * Ee;
    const int arow = tid >> 1, akh = (tid & 1) * 32;
    const int brow = tid >> 2, bc = (tid & 3) * 16;

    for (int k0 = 0; k0 < Ee; k0 += 64) {
        __syncthreads();
        {
            const u16* asrc = ab + (size_t)arow * Ee + k0 + akh;
#pragma unroll
            for (int j = 0; j < 4; ++j)
                *(uint4*)&As[arow][akh + 8 * j] = *(const uint4*)(asrc + 8 * j);
            const u16* bsrc = Wt + (size_t)(nt * 64 + brow) * 1024 + k0 + bc;
            *(uint4*)&Bs[brow][bc]     = *(const uint4*)(bsrc);
            *(uint4*)&Bs[brow][bc + 8] = *(const uint4*)(bsrc + 8);
        }
        __syncthreads();
#pragma unroll
        for (int kc = 0; kc < 4; ++kc) {
            bf16x8 af = ld_frag(&As[wid * 32 + l31][kc * 16 + khalf]);
#pragma unroll
            for (int ct = 0; ct < 2; ++ct) {
                bf16x8 bf = ld_frag(&Bs[ct * 32 + l31][kc * 16 + khalf]);
                acc[ct] = __builtin_amdgcn_mfma_f32_32x32x16_bf16(af, bf, acc[ct], 0, 0, 0);
            }
        }
    }

#pragma unroll
    for (int ct = 0; ct < 2; ++ct) {
        int col = nt * 64 + ct * 32 + l31;
        float bv = bias[col];
#pragma unroll
        for (int r = 0; r < 16; ++r) {
            int row_l = (r & 3) + 8 * (r >> 2) + 4 * (lane >> 5);
            int gm = mt * 128 + wid * 32 + row_l;
            out[(size_t)gm * Ee + col] = acc[ct][r] + bv;
        }
    }
}

// ---------------------------------------------------------------------------
extern "C" void kernel_launch(void* const* d_in, const int* in_sizes, int n_in,
                              void* d_out, int out_size, void* d_ws, size_t ws_size,
                              hipStream_t stream) {
    const float* x    = (const float*)d_in[0];  // [2,2048,1024] f32
    const float* Wqkv = (const float*)d_in[1];  // [16,1024,192] f32
    const float* bqkv = (const float*)d_in[2];  // [16,192] f32
    const float* Wout = (const float*)d_in[3];  // [1024,1024] f32
    const float* bout = (const float*)d_in[4];  // [1024] f32
    float* out = (float*)d_out;                 // [2,2048,1024] f32

    const size_t SZ = (size_t)Bz * Hh * Nn * HD;        // 4,194,304 elems
    const size_t NSA = (size_t)Bz * Nn * Ee;            // 4,194,304 elems
    const size_t NEED = (3 * SZ + NSA) * sizeof(u16);   // 32 MiB

    if (ws_size < NEED) {
        ws_diag<<<1, 1, 0, stream>>>(out, 20000.0f + (float)(ws_size >> 20));
        return;
    }

    u16* ws = (u16*)d_ws;
    u16* kbuf  = ws;
    u16* qbuf  = ws + SZ;
    u16* vbuf  = ws + 2 * SZ;
    u16* sabuf = ws + 3 * SZ;
    u16* wqkv_t = sabuf;        // 6 MB in dead sa region (until attn2)
    u16* wout_t = kbuf;         // 2 MB in dead k region (after attn2)
    u16* xbf    = (u16*)d_out;  // 8 MB in dead out region (until out_mfma)

    convert_x<<<2048, 256, 0, stream>>>(x, xbf);
    // Wqkv [h][1024 k][192 n] f32 -> [h][192 n][1024 k] bf16
    transpose_f32_bf16<<<dim3(16, 3, 16), 256, 0, stream>>>(Wqkv, wqkv_t, 1024, 192);
    qkv_mfma<<<dim3(64, 16), 256, 0, stream>>>(xbf, wqkv_t, bqkv, kbuf, qbuf, vbuf);
    attn2<<<dim3(16, 32), 256, 0, stream>>>(qbuf, kbuf, vbuf, sabuf);
    // Wout [1024 k][1024 n] f32 -> [1024 n][1024 k] bf16 (kbuf now dead)
    transpose_f32_bf16<<<dim3(16, 16, 1), 256, 0, stream>>>(Wout, wout_t, 1024, 1024);
    out_mfma<<<dim3(32, 16), 256, 0, stream>>>(sabuf, wout_t, bout, out);
}